// Round 13
// baseline (137.075 us; speedup 1.0000x reference)
//
#include <hip/hip_runtime.h>
#include <math.h>

#define BTOT   32768
#define NNODE  78
#define NEMB   30
#define NPROJ  10
#define NGR    7
#define ROW    (NNODE*NEMB)       // 2340 floats per batch
#define BPW    8                  // batches per WG (8 half-waves, 256 thr)
#define FEAT_OUT (BTOT*NGR*NEMB)
#define NWG    (BTOT/BPW)         // 4096
#define APITCH 80                 // attpart row pitch (floats)

__constant__ int d_off[NGR] = {0,5,14,23,48,57,66};
__constant__ int d_len[NGR] = {5,9,9,25,9,9,12};

// ---- cross-lane: 4-step DPP reduce within 16-lane rows; swz16 to bridge A/B ----
template<int CTRL>
__device__ __forceinline__ float dpp_f(float x) {
  return __int_as_float(__builtin_amdgcn_update_dpp(0, __float_as_int(x), CTRL, 0xF, 0xF, true));
}
__device__ __forceinline__ float swz16(float x) {  // lane <-> lane^16
  return __int_as_float(__builtin_amdgcn_ds_swizzle(__float_as_int(x), 0x401F));
}
__device__ __forceinline__ float hsum16(float x) { // sum over 16-lane row, uniform result
  x += dpp_f<0xB1>(x);    // xor1
  x += dpp_f<0x4E>(x);    // xor2
  x += dpp_f<0x141>(x);   // half-mirror (4-groups)
  x += dpp_f<0x140>(x);   // mirror (8-groups)
  return x;
}

// Load NP row-pairs: A-lanes (0-14) take even rows, B-lanes (16-30) odd rows,
// each lane a float2 of its e-pair. One instr covers 2 rows (480B per wave64).
template<int NP>
__device__ __forceinline__ void load_pairs(const float* __restrict__ base,
                                           float2 (&xr)[NP]) {
#pragma unroll
  for (int p = 0; p < NP; ++p)
    xr[p] = *(const float2*)(base + p * (2*NEMB));
}

// One 32-lane half-wave = one (batch, graph). e-pair per lane, rows split by parity.
template<int OFF, int LEN, int G>
__device__ __forceinline__ void compute_graph(
    const float2 (&xr)[(LEN+1)/2],
    const float (&W0)[NPROJ], const float (&W1)[NPROJ],
    float* __restrict__ arow, float* __restrict__ outb,
    bool isB, int lmod)
{
  constexpr int NP  = (LEN+1)/2;   // pairs (A rows)
  constexpr int NB  = LEN/2;       // valid B rows
  constexpr bool ODD = (LEN & 1);

  // partial xsum over own-parity rows (mask B's phantom last row for odd LEN)
  float xs0 = 0.f, xs1 = 0.f;
#pragma unroll
  for (int p = 0; p < NP; ++p) {
    float mk = (ODD && p == NP-1) ? (isB ? 0.f : 1.f) : 1.f;
    xs0 += mk * xr[p].x;
    xs1 += mk * xr[p].y;
  }
  xs0 += swz16(xs0);               // full xsum for this e-pair
  xs1 += swz16(xs1);
  // t[h] = sum_e W[e,h]*xsum[e]  (W=0 in lanes 15,31 kills garbage)
  float t[NPROJ];
#pragma unroll
  for (int h = 0; h < NPROJ; ++h)
    t[h] = hsum16(fmaf(W1[h], xs1, W0[h]*xs0));
  // u for own e-pair
  float u0 = 0.f, u1 = 0.f;
#pragma unroll
  for (int h = 0; h < NPROJ; ++h) { u0 = fmaf(W0[h], t[h], u0); u1 = fmaf(W1[h], t[h], u1); }
  // logits of own-parity rows (group-uniform after reduce)
  float lg[NP];
#pragma unroll
  for (int p = 0; p < NP; ++p)
    lg[p] = hsum16(fmaf(xr[p].y, u1, xr[p].x * u0));
  // softmax across both parity groups (one swz16 exchange for max and sum)
  float mp = -INFINITY;
#pragma unroll
  for (int p = 0; p < NP; ++p) {
    float v = lg[p];
    if (ODD && p == NP-1 && isB) v = -INFINITY;
    mp = fmaxf(mp, v);
  }
  float m = fmaxf(mp, swz16(mp));
  float ex[NP];
  float sp = 0.f;
#pragma unroll
  for (int p = 0; p < NP; ++p) {
    float v = __expf(lg[p] - m);
    if (ODD && p == NP-1 && isB) v = 0.f;
    ex[p] = v; sp += v;
  }
  float inv = 1.f / (sp + swz16(sp));
  // feat partials over own rows, then combine parities
  float f0 = 0.f, f1 = 0.f;
#pragma unroll
  for (int p = 0; p < NP; ++p) {
    float a = ex[p] * inv;
    f0 = fmaf(a, xr[p].x, f0);
    f1 = fmaf(a, xr[p].y, f1);
  }
  f0 += swz16(f0);
  f1 += swz16(f1);
  if (!isB && lmod < 15)
    *(float2*)(outb + G*NEMB + 2*lmod) = make_float2(f0, f1);   // 120B contiguous
  // park att for cross-batch sum: A-lane p -> node OFF+2p, B-lane p<NB -> OFF+2p+1
  float myatt = 0.f; bool wr = false;
#pragma unroll
  for (int p = 0; p < NP; ++p) {
    bool pick = isB ? (p < NB && lmod == p) : (lmod == p);
    if (pick) { myatt = ex[p] * inv; wr = true; }
  }
  if (wr) arow[OFF + 2*lmod + (isB ? 1 : 0)] = myatt;
}

__global__ __launch_bounds__(256) void meso_main(
    const float* __restrict__ x, const float* __restrict__ wt,
    float* __restrict__ out, float* __restrict__ attpart)
{
  __shared__ float att_all[BPW][NNODE];   // 2.4 KB

  const int tid    = threadIdx.x;
  const int half   = tid >> 5;
  const int lane31 = tid & 31;
  const bool isB   = lane31 >= 16;
  const int lmod   = lane31 & 15;
  const int lmodc  = lmod < 15 ? lmod : 14;   // clamp lanes 15/31 to safe addresses
  const bool wvalid = lmod < 15;

  // W rows for this lane's e-pair (zero in lanes 15,31)
  float W0[NPROJ], W1[NPROJ];
#pragma unroll
  for (int h = 0; h < NPROJ; ++h) {
    W0[h] = wvalid ? wt[(2*lmod  )*NPROJ + h] : 0.f;
    W1[h] = wvalid ? wt[(2*lmod+1)*NPROJ + h] : 0.f;
  }

  const long long b = (long long)blockIdx.x * BPW + half;
  const float* xbase = x + b*ROW + (isB ? NEMB : 0) + 2*lmodc;
  float* outb = out + b * (NGR*NEMB);
  float* arow = att_all[half];

  // prefetch-one-ahead pipeline (R12 structure)
  float2 xr0[3], xr1[5], xr2[5], xr3[13], xr4[5], xr5[5], xr6[6];
  load_pairs< 3>(xbase +  0*NEMB, xr0);
  load_pairs< 5>(xbase +  5*NEMB, xr1);
  compute_graph< 0, 5,0>(xr0, W0,W1, arow, outb, isB, lmod);
  load_pairs< 5>(xbase + 14*NEMB, xr2);
  compute_graph< 5, 9,1>(xr1, W0,W1, arow, outb, isB, lmod);
  load_pairs<13>(xbase + 23*NEMB, xr3);
  compute_graph<14, 9,2>(xr2, W0,W1, arow, outb, isB, lmod);
  load_pairs< 5>(xbase + 48*NEMB, xr4);
  compute_graph<23,25,3>(xr3, W0,W1, arow, outb, isB, lmod);
  load_pairs< 5>(xbase + 57*NEMB, xr5);
  compute_graph<48, 9,4>(xr4, W0,W1, arow, outb, isB, lmod);
  load_pairs< 6>(xbase + 66*NEMB, xr6);
  compute_graph<57, 9,5>(xr5, W0,W1, arow, outb, isB, lmod);
  compute_graph<66,12,6>(xr6, W0,W1, arow, outb, isB, lmod);

  __syncthreads();
  // per-WG att sum -> plain coalesced store (no atomics, no init needed)
  if (tid < NNODE) {
    float s = 0.f;
#pragma unroll
    for (int h = 0; h < BPW; ++h) s += att_all[h][tid];
    attpart[(size_t)blockIdx.x * APITCH + tid] = s;
  }
}

// 21 WGs: one per (graph, axis) output. Reduces 4096 WG-partials from L2.
__global__ __launch_bounds__(256) void meso_coor(
    const float* __restrict__ attpart,
    const float* __restrict__ coords,
    float* __restrict__ out_coor)
{
  __shared__ float red[256];
  const int t  = blockIdx.x;            // 0..20
  const int g  = t / 3, kk = t % 3;
  const int off = d_off[g], len = d_len[g];
  const int tid = threadIdx.x;

  float partial = 0.f;
  for (int j = 0; j < len; ++j) {
    float c = coords[(off+j)*3 + kk];
    float s = 0.f;
    for (int w = tid; w < NWG; w += 256)
      s += attpart[(size_t)w * APITCH + off + j];
    partial = fmaf(c, s, partial);
  }
  red[tid] = partial;
  __syncthreads();
#pragma unroll
  for (int k = 128; k > 0; k >>= 1) {
    if (tid < k) red[tid] += red[tid + k];
    __syncthreads();
  }
  if (tid == 0) out_coor[t] = red[0] * (1.0f/(float)BTOT);
}

extern "C" void kernel_launch(void* const* d_in, const int* in_sizes, int n_in,
                              void* d_out, int out_size, void* d_ws, size_t ws_size,
                              hipStream_t stream) {
  const float* x      = (const float*)d_in[0];
  const float* coords = (const float*)d_in[1];
  const float* wt     = (const float*)d_in[2];
  float* out     = (float*)d_out;
  float* attpart = (float*)d_ws;   // 4096*80*4 = 1.31 MB, fully overwritten each call

  meso_main<<<NWG, 256, 0, stream>>>(x, wt, out, attpart);
  meso_coor<<<21, 256, 0, stream>>>(attpart, coords, out + FEAT_OUT);
}